// Round 3
// baseline (257.508 us; speedup 1.0000x reference)
//
#include <hip/hip_runtime.h>
#include <hip/hip_bf16.h>
#include <stdint.h>

#define NB 16
#define JXX 4096
#define JQQ 512
#define DDD 256
#define LOG2E 1.44269504f

typedef __attribute__((ext_vector_type(8))) _Float16 f16x8;
typedef __attribute__((ext_vector_type(4))) _Float16 f16x4;
typedef __attribute__((ext_vector_type(4))) float f32x4;

__device__ __forceinline__ uint16_t f2h(float f) {
    union { _Float16 h; uint16_t s; } u; u.h = (_Float16)f; return u.s;
}
__device__ __forceinline__ float h2f(uint16_t s) {
    union { _Float16 h; uint16_t s; } u; u.s = s; return (float)u.h;
}

// ---------------- mask canonicalization (dtype-detecting) ----------------
__global__ void k_mask(const void* cmask, const void* qmask,
                       uint8_t* cm8, uint8_t* qm8) {
    int i = blockIdx.x * 256 + threadIdx.x;
    uint32_t w0c = *(const uint32_t*)cmask;
    uint32_t w0q = *(const uint32_t*)qmask;
    int mc = (w0c == 1u) ? 1 : (w0c == 0x3f800000u ? 2 : 0);
    int mq = (w0q == 1u) ? 1 : (w0q == 0x3f800000u ? 2 : 0);
    if (i < NB * JXX) {
        uint8_t v;
        if (mc == 1)      v = ((const int*)cmask)[i] != 0;
        else if (mc == 2) v = ((const float*)cmask)[i] != 0.0f;
        else              v = ((const uint8_t*)cmask)[i] != 0;
        cm8[i] = v;
    }
    if (i < NB * JQQ) {
        uint8_t v;
        if (mq == 1)      v = ((const int*)qmask)[i] != 0;
        else if (mq == 2) v = ((const float*)qmask)[i] != 0.0f;
        else              v = ((const uint8_t*)qmask)[i] != 0;
        qm8[i] = v;
    }
}

// ------------- transpose f32 [R][C] -> fp16 [C][R], batched via z -------------
__global__ void k_transpose_to_f16(const float* __restrict__ src,
                                   uint16_t* __restrict__ dst,
                                   int R, int Cc, long sbatch, long dbatch) {
    __shared__ float tile[64][65];
    const float* s = src + (long)blockIdx.z * sbatch;
    uint16_t* d = dst + (long)blockIdx.z * dbatch;
    int r0 = blockIdx.x * 64, c0 = blockIdx.y * 64;
    int t = threadIdx.x;
    #pragma unroll
    for (int i = 0; i < 16; i++) {
        int e = t + 256 * i;
        int r = e >> 6, c = e & 63;
        tile[r][c] = s[(long)(r0 + r) * Cc + c0 + c];
    }
    __syncthreads();
    #pragma unroll
    for (int i = 0; i < 16; i++) {
        int e = t + 256 * i;
        int c = e >> 6, r = e & 63;
        d[(long)(c0 + c) * R + r0 + r] = f2h(tile[r][c]);
    }
}

// ---------------- fused attention: logits -> online softmax -> q_a ----------------
// grid (JX/64, B), 256 thr. wave handles 16 x-rows; j staged 32 at a time.
// Logits mfma: D[j][x], x = lane&15  -> softmax state per-lane (x = l15).
// PV mfma (operands SWAPPED): D[d][x], x = lane&15 -> same lane-x as softmax state.
__global__ __launch_bounds__(256, 2) void k_attn(
    const float* __restrict__ cg,
    const float* __restrict__ qg,
    const uint16_t* __restrict__ qT,   // [B][D][JQ] fp16
    const uint8_t* __restrict__ cm8,
    const uint8_t* __restrict__ qm8,
    uint16_t* __restrict__ qa16)       // [B][JX][D] fp16
{
    __shared__ __align__(16) uint16_t q_lds[32 * 264];    // [j][d] pitch 264 (pad 8)
    __shared__ __align__(16) uint16_t qT_lds[256 * 40];   // [d][j] pitch 40 (pad 8)
    __shared__ __align__(16) uint16_t P_lds[4 * 16 * 40]; // per-wave [x][j] pitch 40
    __shared__ __align__(4)  uint8_t qm_lds[32];

    const int b = blockIdx.y;
    const int t = threadIdx.x;
    const int wave = t >> 6;
    const int lane = t & 63;
    const int l15 = lane & 15;
    const int g = lane >> 4;
    const int xw = blockIdx.x * 64 + wave * 16;

    // c fragments (B operand of logits mfma), resident for whole kernel
    f16x8 cfrag[8];
    {
        const float* crow = cg + ((long)b * JXX + xw + l15) * DDD;
        #pragma unroll
        for (int kb = 0; kb < 8; kb++) {
            float4 v0 = *(const float4*)(crow + kb * 32 + g * 8);
            float4 v1 = *(const float4*)(crow + kb * 32 + g * 8 + 4);
            f16x8 f;
            f[0] = (_Float16)v0.x; f[1] = (_Float16)v0.y; f[2] = (_Float16)v0.z; f[3] = (_Float16)v0.w;
            f[4] = (_Float16)v1.x; f[5] = (_Float16)v1.y; f[6] = (_Float16)v1.z; f[7] = (_Float16)v1.w;
            cfrag[kb] = f;
        }
    }
    const bool cvalid = cm8[(long)b * JXX + xw + l15] != 0;
    float m_run = cvalid ? -1e30f : 0.0f;
    float s_run = 0.0f;
    const f32x4 fzero = {0.f, 0.f, 0.f, 0.f};
    f32x4 qa[16];   // qa[dt][r] = q_a^T[d = dt*16 + g*4 + r][x = l15]
    #pragma unroll
    for (int i = 0; i < 16; i++) qa[i] = fzero;

    for (int jt = 0; jt < 16; jt++) {
        __syncthreads();
        // ---- stage: q rows (f32->fp16), qT copy, mask bytes ----
        {
            const float* qb = qg + ((long)b * JQQ + jt * 32) * DDD;
            #pragma unroll
            for (int i = 0; i < 4; i++) {
                int idx = t + 256 * i;
                int row = idx >> 5, c8 = idx & 31;
                const float* p = qb + row * DDD + c8 * 8;
                float4 v0 = *(const float4*)p;
                float4 v1 = *(const float4*)(p + 4);
                f16x8 f;
                f[0] = (_Float16)v0.x; f[1] = (_Float16)v0.y; f[2] = (_Float16)v0.z; f[3] = (_Float16)v0.w;
                f[4] = (_Float16)v1.x; f[5] = (_Float16)v1.y; f[6] = (_Float16)v1.z; f[7] = (_Float16)v1.w;
                *(f16x8*)(q_lds + row * 264 + c8 * 8) = f;
            }
            const uint16_t* qTb = qT + (long)b * DDD * JQQ + jt * 32;
            #pragma unroll
            for (int i = 0; i < 4; i++) {
                int idx = t + 256 * i;
                int d = idx >> 2, gg = idx & 3;
                *(f16x8*)(qT_lds + d * 40 + gg * 8) =
                    *(const f16x8*)(qTb + (long)d * JQQ + gg * 8);
            }
            if (t < 32) qm_lds[t] = qm8[(long)b * JQQ + jt * 32 + t];
        }
        __syncthreads();

        // ---- logits: D[j][x] = q . c  (x = l15, j = g*4 + r + js*16) ----
        f32x4 acc[2];
        #pragma unroll
        for (int js = 0; js < 2; js++) {
            f32x4 a = fzero;
            const uint16_t* qrow = q_lds + (js * 16 + l15) * 264;
            #pragma unroll
            for (int kb = 0; kb < 8; kb++) {
                f16x8 qf = *(const f16x8*)(qrow + kb * 32 + g * 8);
                a = __builtin_amdgcn_mfma_f32_16x16x32_f16(qf, cfrag[kb], a, 0, 0, 0);
            }
            acc[js] = a;
        }

        // ---- online softmax over this 32-j chunk (state per x = l15) ----
        uint32_t qmw0 = *(const uint32_t*)(qm_lds + g * 4);
        uint32_t qmw1 = *(const uint32_t*)(qm_lds + 16 + g * 4);
        float lmax = -1e30f;
        #pragma unroll
        for (int r = 0; r < 4; r++) {
            bool qv0 = (qmw0 >> (8 * r)) & 0xffu;
            bool qv1 = (qmw1 >> (8 * r)) & 0xffu;
            lmax = fmaxf(lmax, qv0 ? acc[0][r] : -1e30f);
            lmax = fmaxf(lmax, qv1 ? acc[1][r] : -1e30f);
        }
        lmax = fmaxf(lmax, __shfl_xor(lmax, 16));
        lmax = fmaxf(lmax, __shfl_xor(lmax, 32));
        float m_new = cvalid ? fmaxf(m_run, lmax) : 0.0f;
        float fsc = exp2f((m_run - m_new) * LOG2E);
        float psum = 0.0f;
        uint16_t pb[8];
        #pragma unroll
        for (int js = 0; js < 2; js++) {
            uint32_t qmw = js ? qmw1 : qmw0;
            #pragma unroll
            for (int r = 0; r < 4; r++) {
                bool qv = (qmw >> (8 * r)) & 0xffu;
                float p = qv ? exp2f((acc[js][r] - m_new) * LOG2E) : 0.0f;
                if (!cvalid) p = 1.0f;   // c-invalid row: uniform over ALL j
                psum += p;
                pb[js * 4 + r] = f2h(p);
            }
        }
        if (!__all(fsc == 1.0f)) {
            s_run *= fsc;
            #pragma unroll
            for (int i = 0; i < 16; i++) {
                qa[i][0] *= fsc; qa[i][1] *= fsc; qa[i][2] *= fsc; qa[i][3] *= fsc;
            }
        }
        s_run += psum;
        m_run = m_new;

        // ---- P re-layout via per-wave LDS, then PV mfma (swapped operands) ----
        uint16_t* Pw = P_lds + wave * 640 + l15 * 40;   // row x = l15, j = ...
        uint16_t pv0[4] = {pb[0], pb[1], pb[2], pb[3]};
        uint16_t pv1[4] = {pb[4], pb[5], pb[6], pb[7]};
        *(ushort1*)(Pw + g * 4 + 0) = make_ushort1(pv0[0]);
        Pw[g * 4 + 0] = pb[0]; Pw[g * 4 + 1] = pb[1];
        Pw[g * 4 + 2] = pb[2]; Pw[g * 4 + 3] = pb[3];
        Pw[16 + g * 4 + 0] = pb[4]; Pw[16 + g * 4 + 1] = pb[5];
        Pw[16 + g * 4 + 2] = pb[6]; Pw[16 + g * 4 + 3] = pb[7];
        // pa: B-operand, B[k=j][col=x]: lane holds P[x=l15][j=g*8+i]
        f16x8 pa = *(const f16x8*)(P_lds + wave * 640 + l15 * 40 + g * 8);
        #pragma unroll
        for (int dt = 0; dt < 16; dt++) {
            // bq: A-operand, A[row=d][k=j]: lane holds qT[d=dt*16+l15][j=g*8+i]
            f16x8 bq = *(const f16x8*)(qT_lds + (dt * 16 + l15) * 40 + g * 8);
            qa[dt] = __builtin_amdgcn_mfma_f32_16x16x32_f16(bq, pa, qa[dt], 0, 0, 0);
        }
    }

    // ---- finalize: divide by per-x sum (per-lane), store fp16 q_a ----
    float s_tot = s_run + __shfl_xor(s_run, 16);
    s_tot = s_tot + __shfl_xor(s_tot, 32);
    float inv = 1.0f / s_tot;
    uint16_t* outp = qa16 + ((long)b * JXX + xw + l15) * DDD;
    #pragma unroll
    for (int dt = 0; dt < 16; dt++) {
        f16x4 v;
        v[0] = (_Float16)(qa[dt][0] * inv);
        v[1] = (_Float16)(qa[dt][1] * inv);
        v[2] = (_Float16)(qa[dt][2] * inv);
        v[3] = (_Float16)(qa[dt][3] * inv);
        *(f16x4*)(outp + dt * 16 + g * 4) = v;
    }
}

// ---------------- fused SFU: cc@Wr, cc@Wg, tanh/sigmoid blend ----------------
// grid (M/64, 2), 256 thr. K iterated d-major: per d-range build all 4 components.
__global__ __launch_bounds__(256, 2) void k_sfu(
    const float* __restrict__ cg,
    const uint16_t* __restrict__ qa16,
    const uint16_t* __restrict__ WrT,   // [256][1024] fp16 = [n][k]
    const uint16_t* __restrict__ WgT,
    const float* __restrict__ Brb,
    const float* __restrict__ Bgb,
    float* __restrict__ outg)
{
    __shared__ __align__(16) uint16_t c_lds[64 * 72];
    __shared__ __align__(16) uint16_t qa_lds[64 * 72];
    __shared__ __align__(16) uint16_t wr_lds[128 * 72];
    __shared__ __align__(16) uint16_t wg_lds[128 * 72];

    const int t = threadIdx.x;
    const int wave = t >> 6;
    const int lane = t & 63;
    const int l15 = lane & 15, g = lane >> 4;
    const int mw = wave & 1, nw = wave >> 1;
    const long m0 = (long)blockIdx.x * 64;
    const int n0 = blockIdx.y * 128;

    const f32x4 fzero = {0.f, 0.f, 0.f, 0.f};
    f32x4 accR[2][4], accG[2][4];
    #pragma unroll
    for (int a = 0; a < 2; a++)
        #pragma unroll
        for (int bq = 0; bq < 4; bq++) { accR[a][bq] = fzero; accG[a][bq] = fzero; }

    for (int dt = 0; dt < 4; dt++) {
        __syncthreads();
        // stage raw c (f32->fp16) and qa (fp16 copy) for this d-range
        #pragma unroll
        for (int i = 0; i < 2; i++) {
            int idx = t + 256 * i;
            int row = idx >> 3, c8 = idx & 7;
            const float* p = cg + (m0 + row) * DDD + dt * 64 + c8 * 8;
            float4 v0 = *(const float4*)p;
            float4 v1 = *(const float4*)(p + 4);
            f16x8 f;
            f[0] = (_Float16)v0.x; f[1] = (_Float16)v0.y; f[2] = (_Float16)v0.z; f[3] = (_Float16)v0.w;
            f[4] = (_Float16)v1.x; f[5] = (_Float16)v1.y; f[6] = (_Float16)v1.z; f[7] = (_Float16)v1.w;
            *(f16x8*)(c_lds + row * 72 + c8 * 8) = f;
            *(f16x8*)(qa_lds + row * 72 + c8 * 8) =
                *(const f16x8*)(qa16 + (m0 + row) * DDD + dt * 64 + c8 * 8);
        }
        for (int comp = 0; comp < 4; comp++) {
            __syncthreads();
            int k0 = comp * 256 + dt * 64;
            #pragma unroll
            for (int i = 0; i < 4; i++) {
                int idx = t + 256 * i;
                int n = idx >> 3, c8 = idx & 7;
                *(f16x8*)(wr_lds + n * 72 + c8 * 8) =
                    *(const f16x8*)(WrT + (long)(n0 + n) * 1024 + k0 + c8 * 8);
                *(f16x8*)(wg_lds + n * 72 + c8 * 8) =
                    *(const f16x8*)(WgT + (long)(n0 + n) * 1024 + k0 + c8 * 8);
            }
            __syncthreads();
            #pragma unroll
            for (int kb = 0; kb < 2; kb++) {
                f16x8 af[2];
                #pragma unroll
                for (int mf = 0; mf < 2; mf++) {
                    int row = mw * 32 + mf * 16 + l15;
                    f16x8 cf = *(const f16x8*)(c_lds + row * 72 + kb * 32 + g * 8);
                    f16x8 qf = *(const f16x8*)(qa_lds + row * 72 + kb * 32 + g * 8);
                    f16x8 a;
                    if (comp == 0) a = cf;
                    else if (comp == 1) a = qf;
                    else if (comp == 2) a = cf * qf;   // packed f16 mul
                    else a = cf - qf;                  // packed f16 sub
                    af[mf] = a;
                }
                #pragma unroll
                for (int nt = 0; nt < 4; nt++) {
                    int n = nw * 64 + nt * 16 + l15;
                    f16x8 br = *(const f16x8*)(wr_lds + n * 72 + kb * 32 + g * 8);
                    f16x8 bg = *(const f16x8*)(wg_lds + n * 72 + kb * 32 + g * 8);
                    #pragma unroll
                    for (int mf = 0; mf < 2; mf++) {
                        accR[mf][nt] = __builtin_amdgcn_mfma_f32_16x16x32_f16(af[mf], br, accR[mf][nt], 0, 0, 0);
                        accG[mf][nt] = __builtin_amdgcn_mfma_f32_16x16x32_f16(af[mf], bg, accG[mf][nt], 0, 0, 0);
                    }
                }
            }
        }
    }
    // epilogue: D row = g*4 + r (m), col = l15 (n)
    #pragma unroll
    for (int nt = 0; nt < 4; nt++) {
        int n = n0 + nw * 64 + nt * 16 + l15;
        float br = Brb[n], bg = Bgb[n];
        #pragma unroll
        for (int mf = 0; mf < 2; mf++) {
            long rowb = m0 + mw * 32 + mf * 16 + g * 4;
            #pragma unroll
            for (int r = 0; r < 4; r++) {
                float pr = accR[mf][nt][r] + br;
                float pg = accG[mf][nt][r] + bg;
                float x = fminf(fmaxf(pr, -30.f), 30.f);
                float e2 = __expf(2.f * x);
                float rr = (e2 - 1.f) / (e2 + 1.f);
                float gv = 1.0f / (1.0f + __expf(-pg));
                float cv = cg[(rowb + r) * DDD + n];
                outg[(rowb + r) * DDD + n] = gv * rr + (1.f - gv) * cv;
            }
        }
    }
}

extern "C" void kernel_launch(void* const* d_in, const int* in_sizes, int n_in,
                              void* d_out, int out_size, void* d_ws, size_t ws_size,
                              hipStream_t stream) {
    const float* c  = (const float*)d_in[0];
    const float* q  = (const float*)d_in[1];
    const float* Wr = (const float*)d_in[2];
    const float* Br = (const float*)d_in[3];
    const float* Wg = (const float*)d_in[4];
    const float* Bg = (const float*)d_in[5];
    const void* cmask = d_in[6];
    const void* qmask = d_in[7];

    char* ws = (char*)d_ws;
    uint16_t* qT16  = (uint16_t*)(ws + 0);          //  4,194,304 B
    uint16_t* qa16  = (uint16_t*)(ws + 4194304);    // 33,554,432 B
    uint16_t* WrT16 = (uint16_t*)(ws + 37748736);   //    524,288 B
    uint16_t* WgT16 = (uint16_t*)(ws + 38273024);   //    524,288 B
    uint8_t*  cm8   = (uint8_t*)(ws + 38797312);    //     65,536 B
    uint8_t*  qm8   = (uint8_t*)(ws + 38862848);    //      8,192 B
    (void)in_sizes; (void)n_in; (void)out_size; (void)ws_size;

    k_mask<<<dim3((NB * JXX + 255) / 256), dim3(256), 0, stream>>>(cmask, qmask, cm8, qm8);
    // q [512][256] -> qT [256][512], per batch
    k_transpose_to_f16<<<dim3(8, 4, NB), dim3(256), 0, stream>>>(
        q, qT16, JQQ, DDD, (long)JQQ * DDD, (long)DDD * JQQ);
    // Wr/Wg [1024][256] -> [256][1024]
    k_transpose_to_f16<<<dim3(16, 4, 1), dim3(256), 0, stream>>>(Wr, WrT16, 1024, 256, 0, 0);
    k_transpose_to_f16<<<dim3(16, 4, 1), dim3(256), 0, stream>>>(Wg, WgT16, 1024, 256, 0, 0);
    k_attn<<<dim3(JXX / 64, NB), dim3(256), 0, stream>>>(c, q, qT16, cm8, qm8, qa16);
    k_sfu<<<dim3((NB * JXX) / 64, 2), dim3(256), 0, stream>>>(
        c, qa16, WrT16, WgT16, Br, Bg, (float*)d_out);
}